// Round 1
// baseline (32.742 us; speedup 1.0000x reference)
//
#include <hip/hip_runtime.h>

#define NROWS 4096
#define DCOLS 512
#define EPSF 1e-8f

// Reduce three per-thread floats across a 512-thread block.
// Wave(64)-level shuffle reduce, then cross-wave via LDS; result broadcast to all threads.
__device__ __forceinline__ void block_reduce3(float& a, float& b, float& c, float* lds) {
    #pragma unroll
    for (int off = 32; off > 0; off >>= 1) {
        a += __shfl_down(a, off, 64);
        b += __shfl_down(b, off, 64);
        c += __shfl_down(c, off, 64);
    }
    const int lane = threadIdx.x & 63;
    const int wave = threadIdx.x >> 6;
    if (lane == 0) {
        lds[wave * 3 + 0] = a;
        lds[wave * 3 + 1] = b;
        lds[wave * 3 + 2] = c;
    }
    __syncthreads();
    float ra = 0.f, rb = 0.f, rc = 0.f;
    #pragma unroll
    for (int w = 0; w < 8; ++w) {
        ra += lds[w * 3 + 0];
        rb += lds[w * 3 + 1];
        rc += lds[w * 3 + 2];
    }
    a = ra; b = rb; c = rc;
    __syncthreads();  // safe LDS reuse next iteration
}

// Each block handles NROWS/gridDim.x consecutive rows; thread t owns column t.
// Accumulates per-column sums of normalized x and y rows (fp64), plus the
// diagonal  sum_n (x_n . y_n) / (|x_n| |y_n|)  (fp64).
__global__ __launch_bounds__(512) void cosloss_main(const float* __restrict__ x,
                                                    const float* __restrict__ y,
                                                    double* __restrict__ sx,
                                                    double* __restrict__ sy,
                                                    double* __restrict__ diag) {
    __shared__ float lds[24];
    const int t = threadIdx.x;
    const int rows_per_block = NROWS / gridDim.x;
    const int row0 = blockIdx.x * rows_per_block;

    double psx = 0.0, psy = 0.0, pdiag = 0.0;

    for (int r = 0; r < rows_per_block; ++r) {
        const size_t base = (size_t)(row0 + r) * DCOLS + t;
        const float xv = x[base];
        const float yv = y[base];
        float sxx = xv * xv;
        float syy = yv * yv;
        float sxy = xv * yv;
        block_reduce3(sxx, syy, sxy, lds);
        const float inx = 1.0f / fmaxf(sqrtf(sxx), EPSF);
        const float iny = 1.0f / fmaxf(sqrtf(syy), EPSF);
        psx += (double)(xv * inx);
        psy += (double)(yv * iny);
        if (t == 0) pdiag += (double)sxy * (double)inx * (double)iny;
    }

    atomicAdd(&sx[t], psx);
    atomicAdd(&sy[t], psy);
    if (t == 0) atomicAdd(diag, pdiag);
}

// Single block: dot(sx, sy) in fp64, subtract diag, divide by N^2, write fp32.
__global__ __launch_bounds__(512) void cosloss_final(const double* __restrict__ sx,
                                                     const double* __restrict__ sy,
                                                     const double* __restrict__ diag,
                                                     float* __restrict__ out) {
    __shared__ double lds[8];
    const int t = threadIdx.x;
    double v = sx[t] * sy[t];
    #pragma unroll
    for (int off = 32; off > 0; off >>= 1) v += __shfl_down(v, off, 64);
    const int lane = threadIdx.x & 63;
    const int wave = threadIdx.x >> 6;
    if (lane == 0) lds[wave] = v;
    __syncthreads();
    if (t == 0) {
        double total = 0.0;
        #pragma unroll
        for (int w = 0; w < 8; ++w) total += lds[w];
        const double n2 = (double)NROWS * (double)NROWS;
        out[0] = (float)((total - diag[0]) / n2);
    }
}

extern "C" void kernel_launch(void* const* d_in, const int* in_sizes, int n_in,
                              void* d_out, int out_size, void* d_ws, size_t ws_size,
                              hipStream_t stream) {
    const float* x = (const float*)d_in[0];
    const float* y = (const float*)d_in[1];
    float* out = (float*)d_out;

    double* sx   = (double*)d_ws;          // 512 doubles
    double* sy   = sx + DCOLS;             // 512 doubles
    double* diag = sy + DCOLS;             // 1 double

    // Zero fp64 accumulators every call (harness does not re-poison between replays).
    hipMemsetAsync(d_ws, 0, (2 * DCOLS + 1) * sizeof(double), stream);

    cosloss_main<<<512, 512, 0, stream>>>(x, y, sx, sy, diag);
    cosloss_final<<<1, 512, 0, stream>>>(sx, sy, diag, out);
}

// Round 2
// 20.894 us; speedup vs baseline: 1.5670x; 1.5670x over previous
//
#include <hip/hip_runtime.h>

#define NROWS 4096
#define DCOLS 512
#define NBLK  256            // main-kernel blocks
#define ROWS_PER_BLOCK (NROWS / NBLK)   // 16
#define EPSF 1e-8f

// ---------------------------------------------------------------------------
// Kernel 1: 256 blocks x 512 threads (8 waves). One wave per row, 2 rows/wave.
// Lane l of a wave owns columns {4l..4l+3} and {256+4l..256+4l+3} (two float4).
// Per row: wave-butterfly-reduce (sum x^2, sum y^2, sum x*y), then accumulate
// normalized per-column partials in registers (fp32).
// Block epilogue: combine 8 waves' column partials via LDS, write one
// 512-float partial row for x and y (+1 diag float) per block. No atomics,
// no zero-init required (pure overwrite).
// ---------------------------------------------------------------------------
__global__ __launch_bounds__(512) void cosloss_main(const float4* __restrict__ x4,
                                                    const float4* __restrict__ y4,
                                                    float* __restrict__ partx,
                                                    float* __restrict__ party,
                                                    float* __restrict__ partd) {
    __shared__ float4 smem[8][128];   // 16 KB, reused for x then y
    __shared__ float ldsd[8];

    const int t    = threadIdx.x;
    const int lane = t & 63;
    const int wave = t >> 6;
    const int row0 = blockIdx.x * ROWS_PER_BLOCK + wave * 2;

    float4 psx0 = {0.f, 0.f, 0.f, 0.f}, psx1 = {0.f, 0.f, 0.f, 0.f};
    float4 psy0 = {0.f, 0.f, 0.f, 0.f}, psy1 = {0.f, 0.f, 0.f, 0.f};
    float pdiag = 0.f;

    #pragma unroll
    for (int r = 0; r < 2; ++r) {
        const size_t base = (size_t)(row0 + r) * (DCOLS / 4) + lane;
        const float4 x0 = x4[base];
        const float4 x1 = x4[base + 64];
        const float4 y0 = y4[base];
        const float4 y1 = y4[base + 64];

        float sxx = x0.x*x0.x + x0.y*x0.y + x0.z*x0.z + x0.w*x0.w
                  + x1.x*x1.x + x1.y*x1.y + x1.z*x1.z + x1.w*x1.w;
        float syy = y0.x*y0.x + y0.y*y0.y + y0.z*y0.z + y0.w*y0.w
                  + y1.x*y1.x + y1.y*y1.y + y1.z*y1.z + y1.w*y1.w;
        float sxy = x0.x*y0.x + x0.y*y0.y + x0.z*y0.z + x0.w*y0.w
                  + x1.x*y1.x + x1.y*y1.y + x1.z*y1.z + x1.w*y1.w;

        #pragma unroll
        for (int off = 1; off < 64; off <<= 1) {
            sxx += __shfl_xor(sxx, off, 64);
            syy += __shfl_xor(syy, off, 64);
            sxy += __shfl_xor(sxy, off, 64);
        }

        const float inx = 1.0f / fmaxf(sqrtf(sxx), EPSF);
        const float iny = 1.0f / fmaxf(sqrtf(syy), EPSF);

        psx0.x += x0.x * inx; psx0.y += x0.y * inx; psx0.z += x0.z * inx; psx0.w += x0.w * inx;
        psx1.x += x1.x * inx; psx1.y += x1.y * inx; psx1.z += x1.z * inx; psx1.w += x1.w * inx;
        psy0.x += y0.x * iny; psy0.y += y0.y * iny; psy0.z += y0.z * iny; psy0.w += y0.w * iny;
        psy1.x += y1.x * iny; psy1.y += y1.y * iny; psy1.z += y1.z * iny; psy1.w += y1.w * iny;
        pdiag += sxy * inx * iny;
    }

    // ---- block combine: x column partials ----
    smem[wave][lane]      = psx0;
    smem[wave][64 + lane] = psx1;
    if (lane == 0) ldsd[wave] = pdiag;
    __syncthreads();
    {
        const float* sm = (const float*)smem;
        float s = 0.f;
        #pragma unroll
        for (int w = 0; w < 8; ++w) s += sm[w * 512 + t];
        partx[(size_t)blockIdx.x * DCOLS + t] = s;
    }
    __syncthreads();

    // ---- block combine: y column partials ----
    smem[wave][lane]      = psy0;
    smem[wave][64 + lane] = psy1;
    __syncthreads();
    {
        const float* sm = (const float*)smem;
        float s = 0.f;
        #pragma unroll
        for (int w = 0; w < 8; ++w) s += sm[w * 512 + t];
        party[(size_t)blockIdx.x * DCOLS + t] = s;
    }

    if (t == 0) {
        float d = 0.f;
        #pragma unroll
        for (int w = 0; w < 8; ++w) d += ldsd[w];
        partd[blockIdx.x] = d;
    }
}

// ---------------------------------------------------------------------------
// Kernel 2: one block, 512 threads. Thread t: SX[t], SY[t] over 256 block
// partials (coalesced, L2-resident); v = SX*SY; also fold diag partials.
// Block-reduce, combine, write scalar.
// ---------------------------------------------------------------------------
__global__ __launch_bounds__(512) void cosloss_final(const float* __restrict__ partx,
                                                     const float* __restrict__ party,
                                                     const float* __restrict__ partd,
                                                     float* __restrict__ out) {
    __shared__ float ldsv[8];
    __shared__ float ldsd[8];
    const int t    = threadIdx.x;
    const int lane = t & 63;
    const int wave = t >> 6;

    float sxt = 0.f, syt = 0.f;
    for (int b = 0; b < NBLK; ++b) {
        sxt += partx[(size_t)b * DCOLS + t];
        syt += party[(size_t)b * DCOLS + t];
    }
    float v = sxt * syt;
    float d = (t < NBLK) ? partd[t] : 0.f;

    #pragma unroll
    for (int off = 32; off > 0; off >>= 1) {
        v += __shfl_down(v, off, 64);
        d += __shfl_down(d, off, 64);
    }
    if (lane == 0) { ldsv[wave] = v; ldsd[wave] = d; }
    __syncthreads();
    if (t == 0) {
        double total = 0.0, diag = 0.0;
        #pragma unroll
        for (int w = 0; w < 8; ++w) { total += (double)ldsv[w]; diag += (double)ldsd[w]; }
        const double n2 = (double)NROWS * (double)NROWS;
        out[0] = (float)((total - diag) / n2);
    }
}

extern "C" void kernel_launch(void* const* d_in, const int* in_sizes, int n_in,
                              void* d_out, int out_size, void* d_ws, size_t ws_size,
                              hipStream_t stream) {
    const float4* x4 = (const float4*)d_in[0];
    const float4* y4 = (const float4*)d_in[1];
    float* out = (float*)d_out;

    float* partx = (float*)d_ws;                       // 256*512 floats
    float* party = partx + (size_t)NBLK * DCOLS;       // 256*512 floats
    float* partd = party + (size_t)NBLK * DCOLS;       // 256 floats

    cosloss_main<<<NBLK, 512, 0, stream>>>(x4, y4, partx, party, partd);
    cosloss_final<<<1, 512, 0, stream>>>(partx, party, partd, out);
}

// Round 3
// 14.196 us; speedup vs baseline: 2.3063x; 1.4718x over previous
//
#include <hip/hip_runtime.h>

#define NROWS 4096
#define DCOLS 512
#define NBLK  256                      // main-kernel blocks
#define ROWS_PER_BLOCK (NROWS / NBLK)  // 16
#define EPSF 1e-8f

// ---------------------------------------------------------------------------
// K1: 256 blocks x 512 threads (8 waves). One wave per row, 2 rows/wave.
// Lane l owns columns {4l..4l+3} and {256+4l..256+4l+3} (two float4).
// Per row: wave butterfly reduce (x.x, y.y, x.y), normalize, accumulate
// per-column partials. Block epilogue combines 8 waves via LDS and writes
// TRANSPOSED partials part[col*NBLK + blk] so K2 reads coalesced.
// ---------------------------------------------------------------------------
__global__ __launch_bounds__(512) void cosloss_main(const float4* __restrict__ x4,
                                                    const float4* __restrict__ y4,
                                                    float* __restrict__ partx,
                                                    float* __restrict__ party,
                                                    float* __restrict__ partd) {
    __shared__ float4 smem[8][128];   // 16 KB, reused for x then y
    __shared__ float ldsd[8];

    const int t    = threadIdx.x;
    const int lane = t & 63;
    const int wave = t >> 6;
    const int row0 = blockIdx.x * ROWS_PER_BLOCK + wave * 2;

    float4 psx0 = {0.f,0.f,0.f,0.f}, psx1 = {0.f,0.f,0.f,0.f};
    float4 psy0 = {0.f,0.f,0.f,0.f}, psy1 = {0.f,0.f,0.f,0.f};
    float pdiag = 0.f;

    #pragma unroll
    for (int r = 0; r < 2; ++r) {
        const size_t base = (size_t)(row0 + r) * (DCOLS / 4) + lane;
        const float4 x0 = x4[base];
        const float4 x1 = x4[base + 64];
        const float4 y0 = y4[base];
        const float4 y1 = y4[base + 64];

        float sxx = x0.x*x0.x + x0.y*x0.y + x0.z*x0.z + x0.w*x0.w
                  + x1.x*x1.x + x1.y*x1.y + x1.z*x1.z + x1.w*x1.w;
        float syy = y0.x*y0.x + y0.y*y0.y + y0.z*y0.z + y0.w*y0.w
                  + y1.x*y1.x + y1.y*y1.y + y1.z*y1.z + y1.w*y1.w;
        float sxy = x0.x*y0.x + x0.y*y0.y + x0.z*y0.z + x0.w*y0.w
                  + x1.x*y1.x + x1.y*y1.y + x1.z*y1.z + x1.w*y1.w;

        #pragma unroll
        for (int off = 1; off < 64; off <<= 1) {
            sxx += __shfl_xor(sxx, off, 64);
            syy += __shfl_xor(syy, off, 64);
            sxy += __shfl_xor(sxy, off, 64);
        }

        const float inx = 1.0f / fmaxf(sqrtf(sxx), EPSF);
        const float iny = 1.0f / fmaxf(sqrtf(syy), EPSF);

        psx0.x += x0.x*inx; psx0.y += x0.y*inx; psx0.z += x0.z*inx; psx0.w += x0.w*inx;
        psx1.x += x1.x*inx; psx1.y += x1.y*inx; psx1.z += x1.z*inx; psx1.w += x1.w*inx;
        psy0.x += y0.x*iny; psy0.y += y0.y*iny; psy0.z += y0.z*iny; psy0.w += y0.w*iny;
        psy1.x += y1.x*iny; psy1.y += y1.y*iny; psy1.z += y1.z*iny; psy1.w += y1.w*iny;
        pdiag += sxy * inx * iny;
    }

    // ---- x column partials ----
    smem[wave][lane]      = psx0;
    smem[wave][64 + lane] = psx1;
    if (lane == 0) ldsd[wave] = pdiag;
    __syncthreads();
    {
        const float* sm = (const float*)smem;
        float s = 0.f;
        #pragma unroll
        for (int w = 0; w < 8; ++w) s += sm[w * 512 + t];
        partx[(size_t)t * NBLK + blockIdx.x] = s;   // transposed
    }
    __syncthreads();

    // ---- y column partials ----
    smem[wave][lane]      = psy0;
    smem[wave][64 + lane] = psy1;
    __syncthreads();
    {
        const float* sm = (const float*)smem;
        float s = 0.f;
        #pragma unroll
        for (int w = 0; w < 8; ++w) s += sm[w * 512 + t];
        party[(size_t)t * NBLK + blockIdx.x] = s;   // transposed
    }

    if (t == 0) {
        float d = 0.f;
        #pragma unroll
        for (int w = 0; w < 8; ++w) d += ldsd[w];
        partd[blockIdx.x] = d;
    }
}

// ---------------------------------------------------------------------------
// K2: 64 blocks x 512 threads. Wave w of block b owns column c = b*8 + w.
// Lane l sums partials at [c*NBLK + l + 64*i] (coalesced), wave shuffle
// reduce -> colprod[c] = SX[c] * SY[c].
// ---------------------------------------------------------------------------
__global__ __launch_bounds__(512) void cosloss_mid(const float* __restrict__ partx,
                                                   const float* __restrict__ party,
                                                   float* __restrict__ colprod) {
    const int t    = threadIdx.x;
    const int lane = t & 63;
    const int wave = t >> 6;
    const int c    = blockIdx.x * 8 + wave;

    const float* bx = partx + (size_t)c * NBLK;
    const float* by = party + (size_t)c * NBLK;

    float sx = 0.f, sy = 0.f;
    #pragma unroll
    for (int i = 0; i < 4; ++i) {
        sx += bx[lane + 64 * i];
        sy += by[lane + 64 * i];
    }
    #pragma unroll
    for (int off = 32; off > 0; off >>= 1) {
        sx += __shfl_down(sx, off, 64);
        sy += __shfl_down(sy, off, 64);
    }
    if (lane == 0) colprod[c] = sx * sy;
}

// ---------------------------------------------------------------------------
// K3: 1 block x 512 threads. total = sum(colprod) - sum(partd); scale; write.
// ---------------------------------------------------------------------------
__global__ __launch_bounds__(512) void cosloss_final(const float* __restrict__ colprod,
                                                     const float* __restrict__ partd,
                                                     float* __restrict__ out) {
    __shared__ float ldsv[8];
    __shared__ float ldsd[8];
    const int t    = threadIdx.x;
    const int lane = t & 63;
    const int wave = t >> 6;

    float v = colprod[t];
    float d = (t < NBLK) ? partd[t] : 0.f;

    #pragma unroll
    for (int off = 32; off > 0; off >>= 1) {
        v += __shfl_down(v, off, 64);
        d += __shfl_down(d, off, 64);
    }
    if (lane == 0) { ldsv[wave] = v; ldsd[wave] = d; }
    __syncthreads();
    if (t == 0) {
        double tv = 0.0, td = 0.0;
        #pragma unroll
        for (int w = 0; w < 8; ++w) { tv += (double)ldsv[w]; td += (double)ldsd[w]; }
        const double n2 = (double)NROWS * (double)NROWS;
        out[0] = (float)((tv - td) / n2);
    }
}

extern "C" void kernel_launch(void* const* d_in, const int* in_sizes, int n_in,
                              void* d_out, int out_size, void* d_ws, size_t ws_size,
                              hipStream_t stream) {
    const float4* x4 = (const float4*)d_in[0];
    const float4* y4 = (const float4*)d_in[1];
    float* out = (float*)d_out;

    float* partx   = (float*)d_ws;                     // 512*256 floats
    float* party   = partx + (size_t)DCOLS * NBLK;     // 512*256 floats
    float* partd   = party + (size_t)DCOLS * NBLK;     // 256 floats
    float* colprod = partd + NBLK;                     // 512 floats

    cosloss_main<<<NBLK, 512, 0, stream>>>(x4, y4, partx, party, partd);
    cosloss_mid<<<64, 512, 0, stream>>>(partx, party, colprod);
    cosloss_final<<<1, 512, 0, stream>>>(colprod, partd, out);
}